// Round 14
// baseline (89.865 us; speedup 1.0000x reference)
//
#include <hip/hip_runtime.h>

#define NQ 10

// DIAGNOSTIC ROUND: round-11 kernel (best: 66.75 us) wrapped in a rep=3 loop
// so the qnn dispatch (~60 us) outranks the 39.5 us harness fills and gets
// profiled. asm register barrier on the angle values prevents cross-iteration
// CSE (rule #17); each iteration stores out (identical values, idempotent).
//
// Layout: lane = e&63 (qubits 4..9), reg r = e>>6 (qubits 0..3), v2f v[16].
// Primitives: the r10/r11 proven set (DPP 0xB1/0x4E/0x128, ds_swizzle
// 0x101F/0x401F, ds_bpermute for xor32 + composed CNOT gather).

typedef float v2f __attribute__((ext_vector_type(2)));

template<int CTRL>
__device__ __forceinline__ float dppf(float v) {
    const int i = __float_as_int(v);
    const int r = __builtin_amdgcn_update_dpp(i, i, CTRL, 0xF, 0xF, false);
    return __int_as_float(r);
}
template<int OFF>
__device__ __forceinline__ float swzf(float v) {
    return __int_as_float(__builtin_amdgcn_ds_swizzle(__float_as_int(v), OFF));
}
__device__ __forceinline__ float bpermf(int addr4, float v) {
    return __int_as_float(__builtin_amdgcn_ds_bpermute(addr4, __float_as_int(v)));
}
__device__ __forceinline__ float rdlane(float v, int l) {
    return __int_as_float(__builtin_amdgcn_readlane(__float_as_int(v), l));
}
__device__ __forceinline__ v2f splat(float a) { v2f r; r.x = a; r.y = a; return r; }
__device__ __forceinline__ v2f cmul(v2f a, v2f b) {
    v2f r;
    r.x = a.x * b.x - a.y * b.y;
    r.y = a.x * b.y + a.y * b.x;
    return r;
}

__global__ __launch_bounds__(256) void qnn_kernel(const float* __restrict__ x,
                                                  const float* __restrict__ w,
                                                  float* __restrict__ out,
                                                  int B, int rep) {
    const int lane = threadIdx.x & 63;
    const int b = blockIdx.x * 4 + (threadIdx.x >> 6);
    if (b >= B) return;

    // ---- angle tables: lanes 0..9 RX(x), lanes 0..39 RY weights ----
    float cxv = 1.f, sxv = 0.f, cwv = 1.f, swv = 0.f;
    if (lane < NQ) {
        const float a = 0.5f * x[b * NQ + lane];
        cxv = cosf(a); sxv = sinf(a);
    }
    if (lane < 4 * NQ) {
        const float a = 0.5f * w[lane];
        cwv = cosf(a); swv = sinf(a);
    }

    // lane-only constants (iteration-invariant)
    int t = lane;
    t ^= ((t >> 1) & 1) << 0;
    t ^= ((t >> 2) & 1) << 1;
    t ^= ((t >> 3) & 1) << 2;
    t ^= ((t >> 4) & 1) << 3;
    t ^= ((t >> 5) & 1) << 4;
    const int ga4 = t << 2;
    const int gb4 = (t ^ 32) << 2;
    const int a32 = (lane ^ 32) << 2;
    const bool wrapctl = (lane & 1);

    for (int it = 0; it < rep; ++it) {
        // anti-CSE register barrier: each iteration recomputes the circuit
        asm volatile("" : "+v"(cxv), "+v"(sxv), "+v"(cwv), "+v"(swv));

        // ---- per-qubit 2-vectors after RX(x_q) then layer-0 RY(w0_q) ----
        v2f u0[NQ], u1[NQ];
#pragma unroll
        for (int q = 0; q < NQ; ++q) {
            const float c  = rdlane(cxv, q), s  = rdlane(sxv, q);
            const float ch = rdlane(cwv, q), sh = rdlane(swv, q);
            u0[q].x = ch * c;  u0[q].y = sh * s;
            u1[q].x = sh * c;  u1[q].y = -ch * s;
        }

        // ---- product state ----
        v2f ml = (lane & 1) ? u1[9] : u0[9];
#pragma unroll
        for (int p = 1; p < 6; ++p) {
            const v2f f = ((lane >> p) & 1) ? u1[9 - p] : u0[9 - p];
            ml = cmul(ml, f);
        }
        v2f m01[4], m23[4], tml[4];
#pragma unroll
        for (int j = 0; j < 4; ++j) {
            m01[j] = cmul((j & 1) ? u1[3] : u0[3], (j & 2) ? u1[2] : u0[2]);
            m23[j] = cmul((j & 1) ? u1[1] : u0[1], (j & 2) ? u1[0] : u0[0]);
        }
#pragma unroll
        for (int j = 0; j < 4; ++j) tml[j] = cmul(ml, m01[j]);

        v2f v[16];
#pragma unroll
        for (int r = 0; r < 16; ++r) v[r] = cmul(tml[r & 3], m23[r >> 2]);

        // ---- 3x { CNOT ring ; RY sweep(layer l+1) } ----
#pragma unroll
        for (int l = 0; l < 3; ++l) {
            { v2f tmp;
              tmp = v[8];  v[8]  = v[12]; v[12] = tmp;
              tmp = v[9];  v[9]  = v[13]; v[13] = tmp;
              tmp = v[10]; v[10] = v[14]; v[14] = tmp;
              tmp = v[11]; v[11] = v[15]; v[15] = tmp; }
            { v2f tmp;
              tmp = v[4];  v[4]  = v[6];  v[6]  = tmp;
              tmp = v[5];  v[5]  = v[7];  v[7]  = tmp;
              tmp = v[12]; v[12] = v[14]; v[14] = tmp;
              tmp = v[13]; v[13] = v[15]; v[15] = tmp; }
            { v2f tmp;
              tmp = v[2];  v[2]  = v[3];  v[3]  = tmp;
              tmp = v[6];  v[6]  = v[7];  v[7]  = tmp;
              tmp = v[10]; v[10] = v[11]; v[11] = tmp;
              tmp = v[14]; v[14] = v[15]; v[15] = tmp; }
#pragma unroll
            for (int r = 0; r < 16; ++r) {
                const int a4 = (r & 1) ? gb4 : ga4;
                v[r].x = bpermf(a4, v[r].x);
                v[r].y = bpermf(a4, v[r].y);
            }
#pragma unroll
            for (int r = 0; r < 8; ++r) {
                const v2f a = v[r], c2 = v[r + 8];
                v[r]     = wrapctl ? c2 : a;
                v[r + 8] = wrapctl ? a : c2;
            }

            const int base = (l + 1) * NQ;
#pragma unroll
            for (int q = 0; q < 4; ++q) {
                const v2f C = splat(rdlane(cwv, base + q));
                const v2f S = splat(rdlane(swv, base + q));
                const int m = 1 << (3 - q);
#pragma unroll
                for (int r = 0; r < 16; ++r) {
                    if (!(r & m)) {
                        const int r1 = r | m;
                        const v2f a0 = v[r], a1 = v[r1];
                        v[r]  = C * a0 - S * a1;
                        v[r1] = S * a0 + C * a1;
                    }
                }
            }
            {
                const float c = rdlane(cwv, base + 4);
                const float s = rdlane(swv, base + 4);
                const v2f C = splat(c);
                const v2f SS = splat((lane & 32) ? s : -s);
#pragma unroll
                for (int r = 0; r < 16; ++r) {
                    v2f o; o.x = bpermf(a32, v[r].x); o.y = bpermf(a32, v[r].y);
                    v[r] = C * v[r] + SS * o;
                }
            }
            {
                const float c = rdlane(cwv, base + 5);
                const float s = rdlane(swv, base + 5);
                const v2f C = splat(c);
                const v2f SS = splat((lane & 16) ? s : -s);
#pragma unroll
                for (int r = 0; r < 16; ++r) {
                    v2f o; o.x = swzf<0x401F>(v[r].x); o.y = swzf<0x401F>(v[r].y);
                    v[r] = C * v[r] + SS * o;
                }
            }
            {
                const float c = rdlane(cwv, base + 6);
                const float s = rdlane(swv, base + 6);
                const v2f C = splat(c);
                const v2f SS = splat((lane & 8) ? s : -s);
#pragma unroll
                for (int r = 0; r < 16; ++r) {
                    v2f o; o.x = dppf<0x128>(v[r].x); o.y = dppf<0x128>(v[r].y);
                    v[r] = C * v[r] + SS * o;
                }
            }
            {
                const float c = rdlane(cwv, base + 7);
                const float s = rdlane(swv, base + 7);
                const v2f C = splat(c);
                const v2f SS = splat((lane & 4) ? s : -s);
#pragma unroll
                for (int r = 0; r < 16; ++r) {
                    v2f o; o.x = swzf<0x101F>(v[r].x); o.y = swzf<0x101F>(v[r].y);
                    v[r] = C * v[r] + SS * o;
                }
            }
            {
                const float c = rdlane(cwv, base + 8);
                const float s = rdlane(swv, base + 8);
                const v2f C = splat(c);
                const v2f SS = splat((lane & 2) ? s : -s);
#pragma unroll
                for (int r = 0; r < 16; ++r) {
                    v2f o; o.x = dppf<0x4E>(v[r].x); o.y = dppf<0x4E>(v[r].y);
                    v[r] = C * v[r] + SS * o;
                }
            }
            {
                const float c = rdlane(cwv, base + 9);
                const float s = rdlane(swv, base + 9);
                const v2f C = splat(c);
                const v2f SS = splat((lane & 1) ? s : -s);
#pragma unroll
                for (int r = 0; r < 16; ++r) {
                    v2f o; o.x = dppf<0xB1>(v[r].x); o.y = dppf<0xB1>(v[r].y);
                    v[r] = C * v[r] + SS * o;
                }
            }
        }

        // ---- measurement, ring-3 folded into signs ----
        float p[16];
#pragma unroll
        for (int r = 0; r < 16; ++r) p[r] = v[r].x * v[r].x + v[r].y * v[r].y;

        float S15 = 0.f, S7 = 0.f, S12 = 0.f, S14 = 0.f;
#pragma unroll
        for (int r = 0; r < 16; ++r) {
            const float pr = p[r];
            S15 += (__popc(r) & 1)      ? -pr : pr;
            S7  += (__popc(r & 7) & 1)  ? -pr : pr;
            S12 += (__popc(r & 12) & 1) ? -pr : pr;
            S14 += (__popc(r & 14) & 1) ? -pr : pr;
        }

        const float gAll = (__popc(lane) & 1) ? -1.f : 1.f;
        float acc[NQ];
        acc[0] = gAll * S7;
        acc[1] = S12;
        acc[2] = S14;
        acc[3] = S15;
        acc[4] = ((lane >> 5) & 1) ? -S15 : S15;
        acc[5] = (__popc(lane & 0x30) & 1) ? -S15 : S15;
        acc[6] = (__popc(lane & 0x38) & 1) ? -S15 : S15;
        acc[7] = (__popc(lane & 0x3C) & 1) ? -S15 : S15;
        acc[8] = (__popc(lane & 0x3E) & 1) ? -S15 : S15;
        acc[9] = gAll * S15;

#pragma unroll
        for (int q = 0; q < NQ; ++q) {
            float a = acc[q];
            a += bpermf(a32, a);
            a += swzf<0x401F>(a);
            a += dppf<0x128>(a);
            a += swzf<0x101F>(a);
            a += dppf<0x4E>(a);
            a += dppf<0xB1>(a);
            acc[q] = a;
        }
        if (lane == 0) {
#pragma unroll
            for (int q = 0; q < NQ; ++q) out[b * NQ + q] = acc[q];
        }
    }
}

extern "C" void kernel_launch(void* const* d_in, const int* in_sizes, int n_in,
                              void* d_out, int out_size, void* d_ws, size_t ws_size,
                              hipStream_t stream) {
    const float* x = (const float*)d_in[0];   // [B, 10]
    const float* w = (const float*)d_in[1];   // [40]
    float* out = (float*)d_out;               // [B, 10]
    const int B = in_sizes[0] / NQ;           // 2048
    qnn_kernel<<<(B + 3) / 4, 256, 0, stream>>>(x, w, out, B, 3);
}

// Round 15
// 69.934 us; speedup vs baseline: 1.2850x; 1.2850x over previous
//
#include <hip/hip_runtime.h>

#define NQ 10

// Round-15: 2 independent batch elements per wave (ILP fills the 54% VALU
// idle measured in r14). State v2f v[32]: regs 0..15 = element A, 16..31 =
// element B. RY gates use shared weights -> identical code on 32 regs; only
// construction + measurement are per-element. Layer loop kept rolled
// (#pragma unroll 1) to cap code size; coefficient readlane index is
// wave-uniform SGPR. Primitives: r10/r11/r13 proven set only.
//   xor1 -> DPP 0xB1, xor2 -> 0x4E, xor8 -> row_ror:8 (0x128)
//   xor4 -> DPP chain 0x141 then 0x1B (r13-proven)
//   xor16 -> ds_swizzle 0x401F, xor32 -> ds_bpermute (lane^32)<<2
//   composed CNOT gather -> ds_bpermute
//   epilogue: DPP butterfly + readlane cross-row (r13-proven)

typedef float v2f __attribute__((ext_vector_type(2)));

template<int CTRL>
__device__ __forceinline__ float dppf(float v) {
    const int i = __float_as_int(v);
    const int r = __builtin_amdgcn_update_dpp(i, i, CTRL, 0xF, 0xF, false);
    return __int_as_float(r);
}
template<int OFF>
__device__ __forceinline__ float swzf(float v) {
    return __int_as_float(__builtin_amdgcn_ds_swizzle(__float_as_int(v), OFF));
}
__device__ __forceinline__ float bpermf(int addr4, float v) {
    return __int_as_float(__builtin_amdgcn_ds_bpermute(addr4, __float_as_int(v)));
}
__device__ __forceinline__ float rdlane(float v, int l) {
    return __int_as_float(__builtin_amdgcn_readlane(__float_as_int(v), l));
}
__device__ __forceinline__ float xor4f(float v) {   // xor7 then xor3 = xor4
    return dppf<0x1B>(dppf<0x141>(v));
}
__device__ __forceinline__ v2f splat(float a) { v2f r; r.x = a; r.y = a; return r; }
__device__ __forceinline__ v2f cmul(v2f a, v2f b) {
    v2f r;
    r.x = a.x * b.x - a.y * b.y;
    r.y = a.x * b.y + a.y * b.x;
    return r;
}

__global__ __launch_bounds__(256) void qnn_kernel(const float* __restrict__ x,
                                                  const float* __restrict__ w,
                                                  float* __restrict__ out,
                                                  int B) {
    const int lane = threadIdx.x & 63;
    const int wid  = blockIdx.x * 4 + (threadIdx.x >> 6);
    const int b0   = wid * 2;                 // elements b0 (A) and b0+1 (B)
    if (b0 >= B) return;

    // ---- angle tables ----
    float cwv = 1.f, swv = 0.f;               // shared RY weights
    if (lane < 4 * NQ) {
        const float a = 0.5f * w[lane];
        cwv = cosf(a); swv = sinf(a);
    }
    float cxA = 1.f, sxA = 0.f, cxB = 1.f, sxB = 0.f;   // per-element RX
    if (lane < NQ) {
        const float a0 = 0.5f * x[b0 * NQ + lane];
        cxA = cosf(a0); sxA = sinf(a0);
        const float a1 = 0.5f * x[(b0 + 1) * NQ + lane];
        cxB = cosf(a1); sxB = sinf(a1);
    }

    // ---- product state per element (RX + layer-0 RY folded) ----
    v2f v[32];
#pragma unroll
    for (int s = 0; s < 2; ++s) {
        const float cxv = s ? cxB : cxA;
        const float sxv = s ? sxB : sxA;
        v2f u0[NQ], u1[NQ];
#pragma unroll
        for (int q = 0; q < NQ; ++q) {
            const float c  = rdlane(cxv, q), si = rdlane(sxv, q);
            const float ch = rdlane(cwv, q), sh = rdlane(swv, q);
            u0[q].x = ch * c;  u0[q].y = sh * si;
            u1[q].x = sh * c;  u1[q].y = -ch * si;
        }
        v2f ml = (lane & 1) ? u1[9] : u0[9];
#pragma unroll
        for (int p = 1; p < 6; ++p) {
            const v2f f = ((lane >> p) & 1) ? u1[9 - p] : u0[9 - p];
            ml = cmul(ml, f);
        }
        v2f m01[4], m23[4], tml[4];
#pragma unroll
        for (int j = 0; j < 4; ++j) {
            m01[j] = cmul((j & 1) ? u1[3] : u0[3], (j & 2) ? u1[2] : u0[2]);
            m23[j] = cmul((j & 1) ? u1[1] : u0[1], (j & 2) ? u1[0] : u0[0]);
        }
#pragma unroll
        for (int j = 0; j < 4; ++j) tml[j] = cmul(ml, m01[j]);
#pragma unroll
        for (int r = 0; r < 16; ++r) v[s * 16 + r] = cmul(tml[r & 3], m23[r >> 2]);
    }

    // composed source lane for the q=4..8 CNOT chain; sigma_3 folded
    int t = lane;
    t ^= ((t >> 1) & 1) << 0;
    t ^= ((t >> 2) & 1) << 1;
    t ^= ((t >> 3) & 1) << 2;
    t ^= ((t >> 4) & 1) << 3;
    t ^= ((t >> 5) & 1) << 4;
    const int ga4 = t << 2;
    const int gb4 = (t ^ 32) << 2;
    const int a32 = (lane ^ 32) << 2;
    const bool wrapctl = (lane & 1);

    // ---- 3x { CNOT ring ; RY sweep(layer l+1) } — layer loop kept rolled ----
#pragma unroll 1
    for (int l = 0; l < 3; ++l) {
        // ring q0,q1,q2 renames (both halves)
#pragma unroll
        for (int h = 0; h < 32; h += 16) {
            v2f tmp;
            tmp = v[h+8];  v[h+8]  = v[h+12]; v[h+12] = tmp;
            tmp = v[h+9];  v[h+9]  = v[h+13]; v[h+13] = tmp;
            tmp = v[h+10]; v[h+10] = v[h+14]; v[h+14] = tmp;
            tmp = v[h+11]; v[h+11] = v[h+15]; v[h+15] = tmp;
            tmp = v[h+4];  v[h+4]  = v[h+6];  v[h+6]  = tmp;
            tmp = v[h+5];  v[h+5]  = v[h+7];  v[h+7]  = tmp;
            tmp = v[h+12]; v[h+12] = v[h+14]; v[h+14] = tmp;
            tmp = v[h+13]; v[h+13] = v[h+15]; v[h+15] = tmp;
            tmp = v[h+2];  v[h+2]  = v[h+3];  v[h+3]  = tmp;
            tmp = v[h+6];  v[h+6]  = v[h+7];  v[h+7]  = tmp;
            tmp = v[h+10]; v[h+10] = v[h+11]; v[h+11] = tmp;
            tmp = v[h+14]; v[h+14] = v[h+15]; v[h+15] = tmp;
        }
        // ring q3..q8 fused gather (A's and B's bpermutes interleave in flight)
#pragma unroll
        for (int r = 0; r < 32; ++r) {
            const int a4 = (r & 1) ? gb4 : ga4;
            v[r].x = bpermf(a4, v[r].x);
            v[r].y = bpermf(a4, v[r].y);
        }
        // wrap: ctrl lane bit0, tgt rb3
#pragma unroll
        for (int h = 0; h < 32; h += 16) {
#pragma unroll
            for (int r = 0; r < 8; ++r) {
                const v2f a = v[h + r], c2 = v[h + r + 8];
                v[h + r]     = wrapctl ? c2 : a;
                v[h + r + 8] = wrapctl ? a : c2;
            }
        }

        const int base = (l + 1) * NQ;      // wave-uniform SGPR readlane index
        // q0..q3: register-local
#pragma unroll
        for (int q = 0; q < 4; ++q) {
            const v2f C = splat(rdlane(cwv, base + q));
            const v2f S = splat(rdlane(swv, base + q));
            const int m = 1 << (3 - q);
#pragma unroll
            for (int r = 0; r < 32; ++r) {
                if (!(r & m)) {
                    const int r1 = r | m;
                    const v2f a0 = v[r], a1 = v[r1];
                    v[r]  = C * a0 - S * a1;
                    v[r1] = S * a0 + C * a1;
                }
            }
        }
        // q4 (xor32): ds_bpermute
        {
            const float c = rdlane(cwv, base + 4);
            const float s = rdlane(swv, base + 4);
            const v2f C = splat(c);
            const v2f SS = splat((lane & 32) ? s : -s);
#pragma unroll
            for (int r = 0; r < 32; ++r) {
                v2f o; o.x = bpermf(a32, v[r].x); o.y = bpermf(a32, v[r].y);
                v[r] = C * v[r] + SS * o;
            }
        }
        // q5 (xor16): ds_swizzle 0x401F
        {
            const float c = rdlane(cwv, base + 5);
            const float s = rdlane(swv, base + 5);
            const v2f C = splat(c);
            const v2f SS = splat((lane & 16) ? s : -s);
#pragma unroll
            for (int r = 0; r < 32; ++r) {
                v2f o; o.x = swzf<0x401F>(v[r].x); o.y = swzf<0x401F>(v[r].y);
                v[r] = C * v[r] + SS * o;
            }
        }
        // q6 (xor8): DPP row_ror:8
        {
            const float c = rdlane(cwv, base + 6);
            const float s = rdlane(swv, base + 6);
            const v2f C = splat(c);
            const v2f SS = splat((lane & 8) ? s : -s);
#pragma unroll
            for (int r = 0; r < 32; ++r) {
                v2f o; o.x = dppf<0x128>(v[r].x); o.y = dppf<0x128>(v[r].y);
                v[r] = C * v[r] + SS * o;
            }
        }
        // q7 (xor4): DPP chain (r13-proven)
        {
            const float c = rdlane(cwv, base + 7);
            const float s = rdlane(swv, base + 7);
            const v2f C = splat(c);
            const v2f SS = splat((lane & 4) ? s : -s);
#pragma unroll
            for (int r = 0; r < 32; ++r) {
                v2f o; o.x = xor4f(v[r].x); o.y = xor4f(v[r].y);
                v[r] = C * v[r] + SS * o;
            }
        }
        // q8 (xor2): DPP quad_perm [2,3,0,1]
        {
            const float c = rdlane(cwv, base + 8);
            const float s = rdlane(swv, base + 8);
            const v2f C = splat(c);
            const v2f SS = splat((lane & 2) ? s : -s);
#pragma unroll
            for (int r = 0; r < 32; ++r) {
                v2f o; o.x = dppf<0x4E>(v[r].x); o.y = dppf<0x4E>(v[r].y);
                v[r] = C * v[r] + SS * o;
            }
        }
        // q9 (xor1): DPP quad_perm [1,0,3,2]
        {
            const float c = rdlane(cwv, base + 9);
            const float s = rdlane(swv, base + 9);
            const v2f C = splat(c);
            const v2f SS = splat((lane & 1) ? s : -s);
#pragma unroll
            for (int r = 0; r < 32; ++r) {
                v2f o; o.x = dppf<0xB1>(v[r].x); o.y = dppf<0xB1>(v[r].y);
                v[r] = C * v[r] + SS * o;
            }
        }
    }

    // ---- measurement per element, ring-3 folded into signs (r11 mapping) ----
    const float gAll = (__popc(lane) & 1) ? -1.f : 1.f;
#pragma unroll
    for (int s = 0; s < 2; ++s) {
        float S15 = 0.f, S7 = 0.f, S12 = 0.f, S14 = 0.f;
#pragma unroll
        for (int r = 0; r < 16; ++r) {
            const v2f a = v[s * 16 + r];
            const float pr = a.x * a.x + a.y * a.y;
            S15 += (__popc(r) & 1)      ? -pr : pr;
            S7  += (__popc(r & 7) & 1)  ? -pr : pr;
            S12 += (__popc(r & 12) & 1) ? -pr : pr;
            S14 += (__popc(r & 14) & 1) ? -pr : pr;
        }
        float acc[NQ];
        acc[0] = gAll * S7;
        acc[1] = S12;
        acc[2] = S14;
        acc[3] = S15;
        acc[4] = ((lane >> 5) & 1) ? -S15 : S15;
        acc[5] = (__popc(lane & 0x30) & 1) ? -S15 : S15;
        acc[6] = (__popc(lane & 0x38) & 1) ? -S15 : S15;
        acc[7] = (__popc(lane & 0x3C) & 1) ? -S15 : S15;
        acc[8] = (__popc(lane & 0x3E) & 1) ? -S15 : S15;
        acc[9] = gAll * S15;

        // DPP butterfly over bits 0-3 + readlane cross-row (r13-proven, 0 DS)
#pragma unroll
        for (int q = 0; q < NQ; ++q) {
            float a = acc[q];
            a += dppf<0x128>(a);   // xor8
            a += xor4f(a);         // xor4
            a += dppf<0x4E>(a);    // xor2
            a += dppf<0xB1>(a);    // xor1
            acc[q] = rdlane(a, 0) + rdlane(a, 16) + rdlane(a, 32) + rdlane(a, 48);
        }
        if (lane == 0) {
#pragma unroll
            for (int q = 0; q < NQ; ++q) out[(b0 + s) * NQ + q] = acc[q];
        }
    }
}

extern "C" void kernel_launch(void* const* d_in, const int* in_sizes, int n_in,
                              void* d_out, int out_size, void* d_ws, size_t ws_size,
                              hipStream_t stream) {
    const float* x = (const float*)d_in[0];   // [B, 10]
    const float* w = (const float*)d_in[1];   // [40]
    float* out = (float*)d_out;               // [B, 10]
    const int B = in_sizes[0] / NQ;           // 2048
    const int waves = (B + 1) / 2;            // 2 elements per wave
    qnn_kernel<<<(waves + 3) / 4, 256, 0, stream>>>(x, w, out, B);
}